// Round 4
// baseline (364.883 us; speedup 1.0000x reference)
//
#include <hip/hip_runtime.h>
#include <hip/hip_bf16.h>
#include <stdint.h>

using bf16 = __hip_bfloat16;
typedef __attribute__((ext_vector_type(4))) float f32x4;
typedef __attribute__((ext_vector_type(8))) short s16x8;   // 8 bf16 = 4 VGPRs
typedef __attribute__((ext_vector_type(4))) short s16x4;   // 4 bf16 = 2 VGPRs

#define MFMA_B16(a, b, c)  __builtin_amdgcn_mfma_f32_16x16x32_bf16((a), (b), (c), 0, 0, 0)
#define MFMA16_B16(a, b, c) __builtin_amdgcn_mfma_f32_16x16x16bf16_1k((a), (b), (c), 0, 0, 0)

// async global->LDS, 16B per lane (wave-uniform base + lane*16; LDS layout
// must be linear in chunk order — m104/m108).
__device__ __forceinline__ void gld_lds16(const bf16* g, bf16* l) {
  __builtin_amdgcn_global_load_lds(
      (const __attribute__((address_space(1))) uint32_t*)g,
      (__attribute__((address_space(3))) uint32_t*)l, 16, 0, 0);
}

__device__ __forceinline__ short bf16r(float f) {   // RNE f32->bf16 bits
  uint32_t u = __float_as_uint(f);
  return (short)((u + 0x7FFFu + ((u >> 16) & 1u)) >> 16);
}

// Problem constants
constexpr int MT = 8192;          // B*T
constexpr int KT = 1024;          // C
// workspace element offsets (bf16 elements)
constexpr size_t Q_OFF  = 0;
constexpr size_t K_OFF  = 8388608;
constexpr size_t VT_OFF = 16777216;   // V stored [B,H,hd,T]
constexpr size_t Y_OFF  = 25165824;   // y [B,T,H,hd] == [M, C]
constexpr size_t XB_OFF = 33554432;
constexpr size_t WA_OFF = 41943040;
constexpr size_t WP_OFF = 45088768;
constexpr size_t BA_OFF = 46137344;
constexpr size_t BP_OFF = 46140416;
constexpr size_t WS_NEED_BYTES = 46141440ull * 2ull;

__device__ __forceinline__ int inputs_are_f32(const uint32_t* __restrict__ x) {
  int hits = 0;
  for (int i = 0; i < 256; ++i) {
    uint32_t lo = x[i] & 0x7FFFu;
    hits += (lo >= 12288u && lo < 17408u) ? 1 : 0;
  }
  return hits < 128;
}

__device__ __forceinline__ uint32_t f32pair_to_bf16(float f0, float f1) {
  uint32_t u0 = __float_as_uint(f0), u1 = __float_as_uint(f1);
  uint32_t h0 = (u0 + 0x7FFFu + ((u0 >> 16) & 1u)) >> 16;   // RNE
  uint32_t h1 = (u1 + 0x7FFFu + ((u1 >> 16) & 1u)) >> 16;
  return (h0 & 0xFFFFu) | (h1 << 16);
}

__global__ void convert_inputs(const uint32_t* __restrict__ x, const uint32_t* __restrict__ wa,
                               const uint32_t* __restrict__ ba, const uint32_t* __restrict__ wp,
                               const uint32_t* __restrict__ bp, uint32_t* __restrict__ ws) {
  __shared__ int sflag;
  if (threadIdx.x == 0) sflag = inputs_are_f32(x);
  __syncthreads();
  const int f32f = sflag;
  const size_t total = 6293504;
  for (size_t i = (size_t)blockIdx.x * blockDim.x + threadIdx.x; i < total;
       i += (size_t)gridDim.x * blockDim.x) {
    const uint32_t* src; size_t j, dst;
    if (i < 4194304)      { src = x;  j = i;           dst = 16777216 + j; }  // XB
    else if (i < 5767168) { src = wa; j = i - 4194304; dst = 20971520 + j; }  // WA
    else if (i < 5768704) { src = ba; j = i - 5767168; dst = 23068672 + j; }  // BA
    else if (i < 6292992) { src = wp; j = i - 5768704; dst = 22544384 + j; }  // WP
    else                  { src = bp; j = i - 6292992; dst = 23070208 + j; }  // BP
    uint32_t w;
    if (f32f) {
      const float* fs = (const float*)src;
      w = f32pair_to_bf16(fs[2 * j], fs[2 * j + 1]);
    } else {
      w = src[j];
    }
    ws[dst] = w;
  }
}

// C = A(MxK) * W(NxK)^T + bias.  m97 structure (unchanged this round).
template <int MODE, int N>
__launch_bounds__(256, 2)
__global__ void gemm_bt(const bf16* __restrict__ A, const bf16* __restrict__ W,
                        const bf16* __restrict__ bias, bf16* __restrict__ outb,
                        const uint32_t* __restrict__ xdet, void* __restrict__ outv) {
  const int tid  = threadIdx.x;
  const int wave = tid >> 6, lane = tid & 63;
  const int quad = lane >> 4, l16 = lane & 15;
  const int wm = wave & 1, wn = wave >> 1;
  const int m0 = blockIdx.y * 128, n0 = blockIdx.x * 128;

  __shared__ __align__(16) bf16 As[128 * 32];
  __shared__ __align__(16) bf16 Bs[128 * 32];
  __shared__ int sflag;
  if (MODE == 0) {
    if (tid == 0) sflag = inputs_are_f32(xdet);
  }
  __syncthreads();
  const int f32o = (MODE == 0) ? sflag : 0;

  const f32x4 fz = {0.f, 0.f, 0.f, 0.f};
  f32x4 acc[4][4];
#pragma unroll
  for (int i = 0; i < 4; ++i)
#pragma unroll
    for (int j = 0; j < 4; ++j) acc[i][j] = fz;

  const bf16* Ab = A + (size_t)m0 * KT;
  const bf16* Wb = W + (size_t)n0 * KT;
  const int c0 = wave * 128 + lane;
  const int c1 = c0 + 64;

  for (int kt = 0; kt < KT / 32; ++kt) {
    const int k0 = kt * 32;
    gld_lds16(Ab + (size_t)(c0 >> 2) * KT + k0 + (c0 & 3) * 8, As + c0 * 8);
    gld_lds16(Ab + (size_t)(c1 >> 2) * KT + k0 + (c1 & 3) * 8, As + c1 * 8);
    gld_lds16(Wb + (size_t)(c0 >> 2) * KT + k0 + (c0 & 3) * 8, Bs + c0 * 8);
    gld_lds16(Wb + (size_t)(c1 >> 2) * KT + k0 + (c1 & 3) * 8, Bs + c1 * 8);
    __syncthreads();

    s16x8 af[4], bf_[4];
#pragma unroll
    for (int i = 0; i < 4; ++i)
      af[i] = *(const s16x8*)(As + (wm * 64 + i * 16 + l16) * 32 + quad * 8);
#pragma unroll
    for (int j = 0; j < 4; ++j)
      bf_[j] = *(const s16x8*)(Bs + (wn * 64 + j * 16 + l16) * 32 + quad * 8);
#pragma unroll
    for (int i = 0; i < 4; ++i)
#pragma unroll
      for (int j = 0; j < 4; ++j)
        acc[i][j] = MFMA_B16(af[i], bf_[j], acc[i][j]);
    __syncthreads();
  }

#pragma unroll
  for (int j = 0; j < 4; ++j) {
    const int n = n0 + wn * 64 + j * 16 + l16;
    const float bv = __bfloat162float(bias[n]);
    if (MODE == 0) {
#pragma unroll
      for (int i = 0; i < 4; ++i) {
        const int mb = m0 + wm * 64 + i * 16 + quad * 4;
#pragma unroll
        for (int r = 0; r < 4; ++r) {
          const float v = acc[i][j][r] + bv;
          const size_t idx = (size_t)(mb + r) * N + n;
          if (f32o) ((float*)outv)[idx] = v;
          else      ((bf16*)outv)[idx] = __float2bfloat16(v);
        }
      }
    } else {
      const int which = n >> 10, cc = n & 1023, h = cc >> 6, d = cc & 63;
#pragma unroll
      for (int i = 0; i < 4; ++i) {
        const int mb = m0 + wm * 64 + i * 16 + quad * 4;
#pragma unroll
        for (int r = 0; r < 4; ++r) {
          const int m = mb + r;
          const int b = m >> 11, t = m & 2047;
          const int bh = b * 16 + h;
          const float v = acc[i][j][r] + bv;
          size_t off;
          if (which == 0)      off = Q_OFF  + ((size_t)bh * 2048 + t) * 64 + d;
          else if (which == 1) off = K_OFF  + ((size_t)bh * 2048 + t) * 64 + d;
          else                 off = VT_OFF + ((size_t)bh * 64 + d) * 2048 + t;
          outb[off] = __float2bfloat16(v);
        }
      }
    }
  }
}

// Flash attention, causal, constant-shift softmax, TRANSPOSED score trick:
//   S^T = K Q^T  (A=K-frag, B=Q-frag) -> C-layout(col=qrow,row=kcol)
//   which IS the B-operand layout of mfma 16x16x16 (k=quad*4+j, n=l16),
//   so P stays in registers: O^T += V^T P^T. No P LDS round-trip.
// One block = (bh, 128 q rows); wave owns 32 q rows (2 groups of 16 = l16).
__launch_bounds__(256, 4)
__global__ void attn_fused(const bf16* __restrict__ qw, const bf16* __restrict__ kw,
                           const bf16* __restrict__ vtw, bf16* __restrict__ yw) {
  const int tid  = threadIdx.x;
  const int wave = tid >> 6, lane = tid & 63;
  const int quad = lane >> 4, l16 = lane & 15;
  const int qt = (int)gridDim.x - 1 - (int)blockIdx.x;  // heavy tiles first
  const int bh = blockIdx.y, b = bh >> 4, h = bh & 15;
  const int q0 = qt * 128;
  const int qr0 = q0 + wave * 32;

  __shared__ __align__(16) bf16 Ks[2][2][64][32];  // [buf][dpanel][krow][d%32]
  __shared__ __align__(16) bf16 Vt[2][2][64][32];  // [buf][kpanel][d][k%32]

  const bf16* Qb = qw + (size_t)bh * 2048 * 64;
  const bf16* Kb = kw + (size_t)bh * 2048 * 64;
  const bf16* Vb = vtw + (size_t)bh * 64 * 2048;

  // Q as B-operand frags (bits identical to A-layout): [g][ks]
  s16x8 qf[2][2];
#pragma unroll
  for (int g = 0; g < 2; ++g)
#pragma unroll
    for (int ks = 0; ks < 2; ++ks)
      qf[g][ks] = *(const s16x8*)(Qb + (size_t)(qr0 + g * 16 + l16) * 64 + ks * 32 + quad * 8);

  const f32x4 fz = {0.f, 0.f, 0.f, 0.f};
  f32x4 ot[2][4];   // O^T accum: lane holds O^T[d=dj*16+quad*4+r][q=qr0+g*16+l16]
  float lsum[2] = {0.f, 0.f};
#pragma unroll
  for (int g = 0; g < 2; ++g)
#pragma unroll
    for (int dj = 0; dj < 4; ++dj) ot[g][dj] = fz;

  const int c0 = wave * 128 + lane, c1 = c0 + 64;
  const int p0 = c0 >> 8, r0 = (c0 >> 2) & 63, s0 = c0 & 3;
  const int p1 = c1 >> 8, r1 = (c1 >> 2) & 63, s1 = c1 & 3;
  const int ntiles = q0 / 64 + 2;

  // prologue: stage tile 0 into buf 0
  gld_lds16(Kb + (size_t)r0 * 64 + p0 * 32 + s0 * 8, (bf16*)Ks[0] + c0 * 8);
  gld_lds16(Kb + (size_t)r1 * 64 + p1 * 32 + s1 * 8, (bf16*)Ks[0] + c1 * 8);
  gld_lds16(Vb + (size_t)r0 * 2048 + p0 * 32 + s0 * 8, (bf16*)Vt[0] + c0 * 8);
  gld_lds16(Vb + (size_t)r1 * 2048 + p1 * 32 + s1 * 8, (bf16*)Vt[0] + c1 * 8);

  const float C1 = 0.18033688011112042f;   // 0.125 * log2(e)
  const float C0 = -23.083120654223414f;   // -16 * log2(e)  (constant shift M=16)

  for (int kt = 0; kt < ntiles; ++kt) {
    const int cur = kt & 1, nxt = cur ^ 1;
    __syncthreads();   // drains vmcnt -> buf[cur] ready; buf[nxt] free to restage
    if (kt + 1 < ntiles) {
      const int kn = (kt + 1) * 64;
      gld_lds16(Kb + (size_t)(kn + r0) * 64 + p0 * 32 + s0 * 8, (bf16*)Ks[nxt] + c0 * 8);
      gld_lds16(Kb + (size_t)(kn + r1) * 64 + p1 * 32 + s1 * 8, (bf16*)Ks[nxt] + c1 * 8);
      gld_lds16(Vb + (size_t)r0 * 2048 + kn + p0 * 32 + s0 * 8, (bf16*)Vt[nxt] + c0 * 8);
      gld_lds16(Vb + (size_t)r1 * 2048 + kn + p1 * 32 + s1 * 8, (bf16*)Vt[nxt] + c1 * 8);
    }
    const int k0 = kt * 64;
    if (k0 <= qr0 + 31) {   // wave has live rows in this tile
      const bool domask = (k0 + 63 > qr0);
#pragma unroll
      for (int m4 = 0; m4 < 4; ++m4) {
        // S^T chunk: 16 kcols x 16 qrows x 2 g
        f32x4 st[2];
        st[0] = fz; st[1] = fz;
#pragma unroll
        for (int ks = 0; ks < 2; ++ks) {
          s16x8 kf = *(const s16x8*)(&Ks[cur][ks][m4 * 16 + l16][quad * 8]);
          st[0] = MFMA_B16(kf, qf[0][ks], st[0]);
          st[1] = MFMA_B16(kf, qf[1][ks], st[1]);
        }
        // softmax (constant shift) + pack directly into 16x16x16 B-frags
        s16x4 pb[2];
        const int krow = k0 + m4 * 16 + quad * 4;
#pragma unroll
        for (int g = 0; g < 2; ++g) {
          const int qrow = qr0 + g * 16 + l16;
#pragma unroll
          for (int r = 0; r < 4; ++r) {
            float t = __builtin_fmaf(st[g][r], C1, C0);
            if (domask && (krow + r > qrow)) t = -512.0f;   // exp2 -> 0
            const float p = __builtin_amdgcn_exp2f(t);
            lsum[g] += p;
            pb[g][r] = bf16r(p);
          }
        }
        // O^T += V^T P^T  (A = V^T frag, k=quad*4+j within this 16-k chunk)
        const int pan = m4 >> 1, ko = (m4 & 1) * 16 + quad * 4;
#pragma unroll
        for (int dj = 0; dj < 4; ++dj) {
          s16x4 vf = *(const s16x4*)(&Vt[cur][pan][dj * 16 + l16][ko]);
          ot[0][dj] = MFMA16_B16(vf, pb[0], ot[0][dj]);
          ot[1][dj] = MFMA16_B16(vf, pb[1], ot[1][dj]);
        }
      }
    }
  }

  // l: within-lane partials cover kcols == quad*4+r (mod 16); reduce across quads
#pragma unroll
  for (int g = 0; g < 2; ++g) {
    lsum[g] += __shfl_xor(lsum[g], 16, 64);
    lsum[g] += __shfl_xor(lsum[g], 32, 64);
  }

  // write y[B,T,H,hd]: lane holds O^T[d=dj*16+quad*4+r][qrow]; 8B stores
#pragma unroll
  for (int g = 0; g < 2; ++g) {
    const int qrow = qr0 + g * 16 + l16;
    const float inv = 1.0f / lsum[g];
    bf16* dst = yw + ((size_t)(b * 2048 + qrow) * 16 + h) * 64;
#pragma unroll
    for (int dj = 0; dj < 4; ++dj) {
      s16x4 o4;
#pragma unroll
      for (int r = 0; r < 4; ++r) o4[r] = bf16r(ot[g][dj][r] * inv);
      *(s16x4*)(dst + dj * 16 + quad * 4) = o4;
    }
  }
}

extern "C" void kernel_launch(void* const* d_in, const int* in_sizes, int n_in,
                              void* d_out, int out_size, void* d_ws, size_t ws_size,
                              hipStream_t stream) {
  bf16* ws = (bf16*)d_ws;
  const uint32_t* xdet = (const uint32_t*)d_in[0];
  const bool have_cvt = ws_size >= WS_NEED_BYTES;

  const bf16 *xb, *wab, *bab, *wpb, *bpb;
  if (have_cvt) {
    convert_inputs<<<2048, 256, 0, stream>>>(
        (const uint32_t*)d_in[0], (const uint32_t*)d_in[1], (const uint32_t*)d_in[2],
        (const uint32_t*)d_in[3], (const uint32_t*)d_in[4], (uint32_t*)d_ws);
    xb = ws + XB_OFF; wab = ws + WA_OFF; bab = ws + BA_OFF;
    wpb = ws + WP_OFF; bpb = ws + BP_OFF;
  } else {
    xb = (const bf16*)d_in[0]; wab = (const bf16*)d_in[1]; bab = (const bf16*)d_in[2];
    wpb = (const bf16*)d_in[3]; bpb = (const bf16*)d_in[4];
  }

  gemm_bt<1, 3072><<<dim3(3072 / 128, MT / 128), 256, 0, stream>>>(
      xb, wab, bab, ws, nullptr, nullptr);
  attn_fused<<<dim3(16, 64), 256, 0, stream>>>(ws + Q_OFF, ws + K_OFF, ws + VT_OFF, ws + Y_OFF);
  gemm_bt<0, 1024><<<dim3(1024 / 128, MT / 128), 256, 0, stream>>>(
      ws + Y_OFF, wpb, bpb, nullptr, xdet, d_out);
}